// Round 6
// baseline (401.770 us; speedup 1.0000x reference)
//
#include <hip/hip_runtime.h>
#include <hip/hip_bf16.h>
#include <hip/hip_fp16.h>

#define NTOT 262144  // 64*64*64 spatial
typedef __hip_bfloat16 bf16;
typedef __attribute__((ext_vector_type(4))) float f32x4;
typedef _Float16 f16x8 __attribute__((ext_vector_type(8)));
typedef unsigned int u32x4 __attribute__((ext_vector_type(4)));

__device__ inline ushort f2bf(float f){ bf16 b = __float2bfloat16(f); return *(ushort*)&b; }
__device__ inline float bf2f(ushort u){ union{unsigned i;float f;}v; v.i = (unsigned)u<<16; return v.f; }
__device__ inline unsigned h2u(__half2 h){ union{__half2 h; unsigned u;}v; v.h=h; return v.u; }
__device__ inline __half2 u2h(unsigned u){ union{unsigned u; __half2 h;}v; v.u=u; return v.h; }
__device__ inline ushort f2h(float f){ __half h = __float2half_rn(f); return *(ushort*)&h; }

// ---- dtype detector: flag=1 if inputs are bf16, 0 if fp32 ----
__global__ void detect_dtype(const ushort* __restrict__ w, int* __restrict__ flag) {
  int tid = threadIdx.x;  // 64 threads
  int sane = 0;
  for (int i = tid; i < 512; i += 64) {
    ushort u = w[2 * i];
    int e = (u >> 7) & 0xff;
    sane += (e == 0 || (e >= 100 && e <= 140)) ? 1 : 0;
  }
#pragma unroll
  for (int off = 32; off > 0; off >>= 1) sane += __shfl_down(sane, off, 64);
  if (tid == 0) *flag = (sane >= 256) ? 1 : 0;
}

// convert small array (fp32 or bf16 per flag) to f16 bits
__global__ void cvt_f16(const void* __restrict__ in, ushort* __restrict__ outw,
                        int n, const int* __restrict__ flag) {
  int f = *flag;
  for (int i = blockIdx.x * 256 + threadIdx.x; i < n; i += gridDim.x * 256) {
    float v = f ? bf2f(((const ushort*)in)[i]) : ((const float*)in)[i];
    outw[i] = f2h(v);
  }
}

// ===== fused transpose + GEMM =====
// C[o][n] = sum_c W[o][c] * X[c][n], K=96, O = 96*OF.  W k-major f16 (global);
// X channel-major (MODE 0: fp32/bf16 per flag; MODE 1: f16).  The former
// standalone transpose96 is fused in: phase A stages the 96c x 64n tile into
// LDS t16 (f16), phase B repacks to Xs[64][104] (n-major, 208B stride -> <=2-way
// banks), then the MFMA loop reads B-fragments from LDS.  Saves the 100MB
// Xt/Vt HBM round-trip per GEMM.  cs epilogue buffer aliases t16 (barrier-
// separated lifetimes).  384 threads = 6 waves.
template<int OF, int MODE, bool DYNOUT>
__global__ __launch_bounds__(384)
void gemm96x(const ushort* __restrict__ W, const void* __restrict__ X,
             void* __restrict__ C, const int* __restrict__ flag) {
  constexpr int CSB = 96 * OF * 72 * 2;     // cs bytes
  constexpr int TB  = 96 * 66 * 2;          // t16 bytes (12672)
  constexpr int UNI = (CSB > TB ? CSB : TB);
  __shared__ __align__(16) char smem[UNI + 64 * 104 * 2];
  ushort (*t16)[66] = (ushort(*)[66])smem;
  ushort (*cs)[72]  = (ushort(*)[72])smem;             // aliases t16 (post-MFMA only)
  ushort (*Xs)[104] = (ushort(*)[104])(smem + UNI);
  const int tid = threadIdx.x;
  const long n0 = (long)blockIdx.x * 64;
  const int wave = tid >> 6, lane = tid & 63;
  const int col = lane & 15, quad = lane >> 4;
  const int f = (MODE == 0 || DYNOUT) ? *flag : 0;

  // --- phase A: stage [96][64] tile as f16 into t16 ---
#pragma unroll
  for (int i = 0; i < 4; i++) {
    int idx = tid + 384 * i;      // 0..1535
    int u = idx & 15, c = idx >> 4;
    ushort h0, h1, h2, h3;
    if (MODE == 0 && !f) {
      float4 q = *(const float4*)((const float*)X + (size_t)c * NTOT + n0 + u * 4);
      h0 = f2h(q.x); h1 = f2h(q.y); h2 = f2h(q.z); h3 = f2h(q.w);
    } else if (MODE == 0) {       // bf16 input
      uint2 q = *(const uint2*)((const ushort*)X + (size_t)c * NTOT + n0 + u * 4);
      h0 = f2h(bf2f((ushort)(q.x & 0xffffu))); h1 = f2h(bf2f((ushort)(q.x >> 16)));
      h2 = f2h(bf2f((ushort)(q.y & 0xffffu))); h3 = f2h(bf2f((ushort)(q.y >> 16)));
    } else {                      // f16 input: raw copy
      uint2 q = *(const uint2*)((const ushort*)X + (size_t)c * NTOT + n0 + u * 4);
      h0 = (ushort)(q.x & 0xffffu); h1 = (ushort)(q.x >> 16);
      h2 = (ushort)(q.y & 0xffffu); h3 = (ushort)(q.y >> 16);
    }
    *(unsigned*)&t16[c][u * 4]     = (unsigned)h0 | ((unsigned)h1 << 16);
    *(unsigned*)&t16[c][u * 4 + 2] = (unsigned)h2 | ((unsigned)h3 << 16);
  }
  __syncthreads();

  // --- phase B: transpose-repack into Xs[n][96] (k-major rows) ---
#pragma unroll
  for (int i = 0; i < 2; i++) {
    int idx = tid + 384 * i;      // 0..767
    int oq = idx % 12, n = idx / 12;
    unsigned d[4];
#pragma unroll
    for (int j = 0; j < 4; j++)
      d[j] = (unsigned)t16[oq * 8 + 2 * j][n] | ((unsigned)t16[oq * 8 + 2 * j + 1][n] << 16);
    *(uint4*)&Xs[n][oq * 8] = make_uint4(d[0], d[1], d[2], d[3]);
  }
  __syncthreads();

  // --- MFMA loop (identical fragment conventions to the old gemm96f) ---
  f32x4 acc[OF][4];
#pragma unroll
  for (int a = 0; a < OF; a++)
#pragma unroll
    for (int b = 0; b < 4; b++) acc[a][b] = (f32x4)0.f;
  const int obase = wave * 16 * OF;
#pragma unroll
  for (int ks = 0; ks < 3; ks++) {
    f16x8 bfrag[4];
#pragma unroll
    for (int nf = 0; nf < 4; nf++)
      bfrag[nf] = *(const f16x8*)&Xs[nf * 16 + col][ks * 32 + quad * 8];
#pragma unroll
    for (int of = 0; of < OF; of++) {
      const int o = obase + of * 16 + col;  // A-row = lane&15
      f16x8 afrag = *(const f16x8*)(W + (size_t)o * 96 + ks * 32 + quad * 8);
#pragma unroll
      for (int nf = 0; nf < 4; nf++)
        acc[of][nf] = __builtin_amdgcn_mfma_f32_16x16x32_f16(afrag, bfrag[nf], acc[of][nf], 0, 0, 0);
    }
  }
  // C/D layout: col = lane&15 (n), row = quad*4 + r (o). Stage in LDS (cs aliases
  // t16 — t16 dead since the barrier after phase B), then coalesced store.
#pragma unroll
  for (int of = 0; of < OF; of++)
#pragma unroll
    for (int nf = 0; nf < 4; nf++)
#pragma unroll
      for (int r = 0; r < 4; r++) {
        int o = obase + of * 16 + quad * 4 + r;
        cs[o][nf * 16 + col] = f2h(acc[of][nf][r]);
      }
  __syncthreads();
  if (!DYNOUT) {
    // f16 out, 16B chunks, nontemporal (written once, consumer >> L2)
#pragma unroll
    for (int i = 0; i < 2 * OF; i++) {
      int idx = tid + 384 * i;
      int o = idx >> 3, u = idx & 7;
      u32x4 v = *(const u32x4*)&cs[o][u * 8];
      __builtin_nontemporal_store(v, (u32x4*)((ushort*)C + (size_t)o * NTOT + n0 + u * 8));
    }
  } else {
#pragma unroll
    for (int i = 0; i < 4; i++) {
      int idx = tid + 384 * i;
      int o = idx >> 4, u = idx & 15;
      uint2 v = *(const uint2*)&cs[o][u * 4];
      __half2 a = u2h(v.x), b = u2h(v.y);
      float f0 = __half2float(a.x), f1 = __half2float(a.y);
      float f2 = __half2float(b.x), f3 = __half2float(b.y);
      if (!f) {
        float4 q = {f0, f1, f2, f3};
        *(float4*)((float*)C + (size_t)o * NTOT + n0 + u * 4) = q;
      } else {
        uint2 q = make_uint2(((unsigned)f2bf(f1) << 16) | f2bf(f0),
                             ((unsigned)f2bf(f3) << 16) | f2bf(f2));
        *(uint2*)((ushort*)C + (size_t)o * NTOT + n0 + u * 4) = q;
      }
    }
  }
}

// depthwise 3x3x3, pad 1, f16 in/out, packed-f16 math.  (R5-proven)
__global__ __launch_bounds__(256)
void dwconv3(const ushort* __restrict__ in, const void* __restrict__ wt,
             ushort* __restrict__ out, const int* __restrict__ flag) {
  const unsigned B = blockIdx.x;           // 0..9215
  const int xcd = B & 7;
  const int s = B >> 3;                    // 0..1151
  const int c = xcd + 8 * (s >> 5);        // 0..287, whole channel per XCD
  const int sp = s & 31;                   // 32 spatial blocks per channel
  const int tid = threadIdx.x;
  const int dq = tid & 7;
  const int w = (sp >> 2) * 8 + ((tid >> 3) & 7);
  const int h0 = (sp & 3) * 16 + (tid >> 6) * 4;   // wave-uniform, 4 rows/thread
  const int d0 = dq * 8;
  __shared__ __half2 wsm2[27];
  if (tid < 27) {
    int f = *flag;
    float wv = f ? bf2f(((const ushort*)wt)[c * 27 + tid])
                 : ((const float*)wt)[c * 27 + tid];
    wsm2[tid] = __floats2half2_rn(wv, wv);
  }
  __syncthreads();
  __half2 wreg[27];
#pragma unroll
  for (int i = 0; i < 27; i++) wreg[i] = wsm2[i];
  const unsigned maskL = (dq == 0) ? 0xFFFF0000u : 0xFFFFFFFFu;  // zero x[-1]
  const unsigned maskR = (dq == 7) ? 0x0000FFFFu : 0xFFFFFFFFu;  // zero x[64]
  __half2 acc[4][4];
#pragma unroll
  for (int r = 0; r < 4; r++)
#pragma unroll
    for (int j = 0; j < 4; j++) acc[r][j] = u2h(0u);
  const size_t cbase = (size_t)c * NTOT;
#pragma unroll
  for (int dw = -1; dw <= 1; dw++) {
    const int ww = w + dw;
    const bool wok = (ww >= 0 && ww <= 63);          // uniform within 8-lane group
    const ushort* rowp = in + cbase + (size_t)ww * 64 + d0;
#pragma unroll
    for (int e = -1; e <= 4; e++) {                  // input rows h0-1 .. h0+4
      const int hh = h0 + e;
      if (hh < 0 || hh > 63) continue;               // wave-uniform
      uint4 u = make_uint4(0u, 0u, 0u, 0u);
      if (wok)
        u = *(const uint4*)(rowp + (size_t)hh * 4096);
      unsigned P = (unsigned)__shfl_up((int)u.w, 1, 8);     // prev lane {x6,x7}
      unsigned N = (unsigned)__shfl_down((int)u.x, 1, 8);   // next lane {x0,x1}
      unsigned S0 = __builtin_amdgcn_perm(u.x, P,   0x05040302) & maskL; // {x-1,x0}
      unsigned S1 = __builtin_amdgcn_perm(u.y, u.x, 0x05040302);         // {x1,x2}
      unsigned S2 = __builtin_amdgcn_perm(u.z, u.y, 0x05040302);         // {x3,x4}
      unsigned S3 = __builtin_amdgcn_perm(u.w, u.z, 0x05040302);         // {x5,x6}
      unsigned R3 = __builtin_amdgcn_perm(N,   u.w, 0x05040302) & maskR; // {x7,x8}
#pragma unroll
      for (int r = (e - 1 < 0 ? 0 : e - 1); r <= (e + 1 > 3 ? 3 : e + 1); r++) {
        const int wb = (e - r + 1) * 9 + (dw + 1) * 3;
        const __half2 wL = wreg[wb], wC = wreg[wb + 1], wR = wreg[wb + 2];
        acc[r][0] = __hfma2(wL, u2h(S0), acc[r][0]); acc[r][0] = __hfma2(wC, u2h(u.x), acc[r][0]); acc[r][0] = __hfma2(wR, u2h(S1), acc[r][0]);
        acc[r][1] = __hfma2(wL, u2h(S1), acc[r][1]); acc[r][1] = __hfma2(wC, u2h(u.y), acc[r][1]); acc[r][1] = __hfma2(wR, u2h(S2), acc[r][1]);
        acc[r][2] = __hfma2(wL, u2h(S2), acc[r][2]); acc[r][2] = __hfma2(wC, u2h(u.z), acc[r][2]); acc[r][2] = __hfma2(wR, u2h(S3), acc[r][2]);
        acc[r][3] = __hfma2(wL, u2h(S3), acc[r][3]); acc[r][3] = __hfma2(wC, u2h(u.w), acc[r][3]); acc[r][3] = __hfma2(wR, u2h(R3), acc[r][3]);
      }
    }
  }
#pragma unroll
  for (int r = 0; r < 4; r++) {
    u32x4 pv = { h2u(acc[r][0]), h2u(acc[r][1]), h2u(acc[r][2]), h2u(acc[r][3]) };
    __builtin_nontemporal_store(pv,
        (u32x4*)(out + cbase + ((size_t)(h0 + r) * 64 + w) * 64 + d0));
  }
}

// per-head Gram: G[hd][0]=q.kT, [1]=q.qT, [2]=k.kT  (each 16x16 fp32, atomic accum)
// 768 blocks (2048 n-range each): 3 blocks/CU for latency hiding.
__global__ __launch_bounds__(256)
void gram16(const ushort* __restrict__ qk, float* __restrict__ G) {
  const int hd = blockIdx.y;
  const int tid = threadIdx.x, wave = tid >> 6, lane = tid & 63;
  const int col = lane & 15, quad = lane >> 4;
  const ushort* qp = qk + (size_t)(hd * 16 + col) * NTOT;
  const ushort* kp = qp + (size_t)96 * NTOT;
  f32x4 aqk = (f32x4)0.f, aqq = (f32x4)0.f, akk = (f32x4)0.f;
  const int nbase = blockIdx.x * 2048 + wave * 32 + quad * 8;
#pragma unroll 4
  for (int it = 0; it < 16; it++) {
    f16x8 qf = *(const f16x8*)(qp + nbase + it * 128);
    f16x8 kf = *(const f16x8*)(kp + nbase + it * 128);
    aqk = __builtin_amdgcn_mfma_f32_16x16x32_f16(qf, kf, aqk, 0, 0, 0);
    aqq = __builtin_amdgcn_mfma_f32_16x16x32_f16(qf, qf, aqq, 0, 0, 0);
    akk = __builtin_amdgcn_mfma_f32_16x16x32_f16(kf, kf, akk, 0, 0, 0);
  }
  __shared__ float red[4][64][12];
#pragma unroll
  for (int r = 0; r < 4; r++) {
    red[wave][lane][r]     = aqk[r];
    red[wave][lane][4 + r] = aqq[r];
    red[wave][lane][8 + r] = akk[r];
  }
  __syncthreads();
  if (wave == 0) {
#pragma unroll
    for (int j = 0; j < 12; j++) {
      float v = red[0][lane][j] + red[1][lane][j] + red[2][lane][j] + red[3][lane][j];
      int sub = j >> 2, r = j & 3;
      atomicAdd(&G[hd * 768 + sub * 256 + (quad * 4 + r) * 16 + col], v);
    }
  }
}

// softmax over Gram + fold W_proj: M[o][hd*16+d] = sum_c wp[o][hd*16+c] * A[hd][c][d]
// 36 blocks: each redundantly computes the tiny softmax and writes one slice.
__global__ __launch_bounds__(256)
void attn_mix(const float* __restrict__ G, const void* __restrict__ wp,
              const void* __restrict__ temp, ushort* __restrict__ M,
              const int* __restrict__ flag) {
  __shared__ float As[6][16][16];
  const int tid = threadIdx.x;
  const int f = *flag;
  if (tid < 96) {
    int hd = tid >> 4, c = tid & 15;
    const float* Gh = G + hd * 768;
    float qn = fmaxf(sqrtf(fmaxf(Gh[256 + c * 17], 0.f)), 1e-12f);
    float t = f ? bf2f(((const ushort*)temp)[hd]) : ((const float*)temp)[hd];
    float lg[16];
    float mx = -1e30f;
#pragma unroll
    for (int d = 0; d < 16; d++) {
      float kn = fmaxf(sqrtf(fmaxf(Gh[512 + d * 17], 0.f)), 1e-12f);
      lg[d] = Gh[c * 16 + d] / (qn * kn) * t;
      mx = fmaxf(mx, lg[d]);
    }
    float s = 0.f;
#pragma unroll
    for (int d = 0; d < 16; d++) { lg[d] = __expf(lg[d] - mx); s += lg[d]; }
    float inv = 1.f / s;
#pragma unroll
    for (int d = 0; d < 16; d++) As[hd][c][d] = lg[d] * inv;
  }
  __syncthreads();
  int idx = blockIdx.x * 256 + tid;    // 36*256 = 9216 = 96*96
  int o = idx / 96, p = idx - o * 96;
  int hd = p >> 4, d = p & 15;
  float s = 0.f;
#pragma unroll
  for (int cc = 0; cc < 16; cc++) {
    float wv = f ? bf2f(((const ushort*)wp)[o * 96 + hd * 16 + cc])
                 : ((const float*)wp)[o * 96 + hd * 16 + cc];
    s += wv * As[hd][cc][d];
  }
  M[idx] = f2h(s);
}

extern "C" void kernel_launch(void* const* d_in, const int* in_sizes, int n_in,
                              void* d_out, int out_size, void* d_ws, size_t ws_size,
                              hipStream_t stream) {
  const void* x      = d_in[0];  // (96, 64,64,64)
  const void* w_qkv  = d_in[1];  // (288, 96)
  const void* w_dw   = d_in[2];  // (288, 27)
  const void* w_proj = d_in[3];  // (96, 96)
  const void* temp   = d_in[4];  // (6)

  const size_t szQKV = (size_t)288 * NTOT * 2;  // 151 MB
  ushort* B1 = (ushort*)d_ws;                   // qkv after 1x1 (f16)
  ushort* B2 = (ushort*)((char*)d_ws + szQKV);  // qkv after dwconv (f16)
  char* tail = (char*)d_ws + 2 * szQKV;
  float*  G    = (float*)tail;                    // 6*768 fp32      (18432 B)
  ushort* M    = (ushort*)(tail + 18432);         // 96*96 f16
  ushort* Wh   = (ushort*)(tail + 36864);         // 288*96 f16      (55296 B)
  int*    flag = (int*)(tail + 92160);
  if (ws_size < 2 * szQKV + 92160 + 256) return;  // fail loudly (zeros out)

  detect_dtype<<<1, 64, 0, stream>>>((const ushort*)w_qkv, flag);
  cvt_f16<<<32, 256, 0, stream>>>(w_qkv, Wh, 288 * 96, flag);
  hipMemsetAsync(G, 0, 4608 * 4, stream);
  gemm96x<3, 0, false><<<4096, 384, 0, stream>>>(Wh, x, B1, flag);
  dwconv3<<<9216, 256, 0, stream>>>(B1, w_dw, B2, flag);
  gram16<<<dim3(128, 6), 256, 0, stream>>>(B2, G);
  attn_mix<<<36, 256, 0, stream>>>(G, w_proj, temp, M, flag);
  gemm96x<1, 1, true><<<4096, 384, 0, stream>>>(M, B2 + (size_t)192 * NTOT, d_out, flag);
}

// Round 7
// 384.251 us; speedup vs baseline: 1.0456x; 1.0456x over previous
//
#include <hip/hip_runtime.h>
#include <hip/hip_bf16.h>
#include <hip/hip_fp16.h>

#define NTOT 262144  // 64*64*64 spatial
typedef __hip_bfloat16 bf16;
typedef __attribute__((ext_vector_type(4))) float f32x4;
typedef _Float16 f16x8 __attribute__((ext_vector_type(8)));
typedef unsigned int u32x4 __attribute__((ext_vector_type(4)));

__device__ inline ushort f2bf(float f){ bf16 b = __float2bfloat16(f); return *(ushort*)&b; }
__device__ inline float bf2f(ushort u){ union{unsigned i;float f;}v; v.i = (unsigned)u<<16; return v.f; }
__device__ inline unsigned h2u(__half2 h){ union{__half2 h; unsigned u;}v; v.h=h; return v.u; }
__device__ inline __half2 u2h(unsigned u){ union{unsigned u; __half2 h;}v; v.u=u; return v.h; }
__device__ inline ushort f2h(float f){ __half h = __float2half_rn(f); return *(ushort*)&h; }

// ---- dtype detector: flag=1 if inputs are bf16, 0 if fp32 ----
__global__ void detect_dtype(const ushort* __restrict__ w, int* __restrict__ flag) {
  int tid = threadIdx.x;  // 64 threads
  int sane = 0;
  for (int i = tid; i < 512; i += 64) {
    ushort u = w[2 * i];
    int e = (u >> 7) & 0xff;
    sane += (e == 0 || (e >= 100 && e <= 140)) ? 1 : 0;
  }
#pragma unroll
  for (int off = 32; off > 0; off >>= 1) sane += __shfl_down(sane, off, 64);
  if (tid == 0) *flag = (sane >= 256) ? 1 : 0;
}

// convert small array (fp32 or bf16 per flag) to f16 bits
__global__ void cvt_f16(const void* __restrict__ in, ushort* __restrict__ outw,
                        int n, const int* __restrict__ flag) {
  int f = *flag;
  for (int i = blockIdx.x * 256 + threadIdx.x; i < n; i += gridDim.x * 256) {
    float v = f ? bf2f(((const ushort*)in)[i]) : ((const float*)in)[i];
    outw[i] = f2h(v);
  }
}

// ===== fused transpose + GEMM, v2 =====
// C[o][n] = sum_c W[o][c] * X[c][n], K=96, O = 96*OF.  W k-major f16 (global);
// X channel-major (MODE 0: fp32/bf16 per flag; MODE 1: f16).
// Phase A stages the 96c x 64n tile into LDS t16[96][66] (f16, stride 33 dwords
// == 1 mod 32).  NO repack pass: the MFMA B-fragments are gathered directly as
// ds_read_u16 from t16 — banks = 8*quad + col/2 (+const) = all 32, col-parity
// pairs share a dword (broadcast) -> conflict-free; all 96 reads are
// compile-time offsets off one lane base.  cs epilogue aliases t16
// (barrier-separated).  LDS = max(96*OF*72, 96*66)*2 B: 41.5 KB (OF=3) -> 3
// blocks/CU; 13.8 KB (OF=1).  384 threads = 6 waves.
template<int OF, int MODE, bool DYNOUT>
__global__ __launch_bounds__(384)
void gemm96x(const ushort* __restrict__ W, const void* __restrict__ X,
             void* __restrict__ C, const int* __restrict__ flag) {
  constexpr int CSB = 96 * OF * 72 * 2;     // cs bytes
  constexpr int TB  = 96 * 66 * 2;          // t16 bytes (12672)
  constexpr int UNI = (CSB > TB ? CSB : TB);
  __shared__ __align__(16) char smem[UNI];
  ushort (*t16)[66] = (ushort(*)[66])smem;
  ushort (*cs)[72]  = (ushort(*)[72])smem;   // aliases t16 (post-MFMA only)
  const int tid = threadIdx.x;
  const long n0 = (long)blockIdx.x * 64;
  const int wave = tid >> 6, lane = tid & 63;
  const int col = lane & 15, quad = lane >> 4;
  const int f = (MODE == 0 || DYNOUT) ? *flag : 0;

  // --- phase A: stage [96][64] tile as f16 into t16 ---
#pragma unroll
  for (int i = 0; i < 4; i++) {
    int idx = tid + 384 * i;      // 0..1535
    int u = idx & 15, c = idx >> 4;
    ushort h0, h1, h2, h3;
    if (MODE == 0 && !f) {
      float4 q = *(const float4*)((const float*)X + (size_t)c * NTOT + n0 + u * 4);
      h0 = f2h(q.x); h1 = f2h(q.y); h2 = f2h(q.z); h3 = f2h(q.w);
    } else if (MODE == 0) {       // bf16 input
      uint2 q = *(const uint2*)((const ushort*)X + (size_t)c * NTOT + n0 + u * 4);
      h0 = f2h(bf2f((ushort)(q.x & 0xffffu))); h1 = f2h(bf2f((ushort)(q.x >> 16)));
      h2 = f2h(bf2f((ushort)(q.y & 0xffffu))); h3 = f2h(bf2f((ushort)(q.y >> 16)));
    } else {                      // f16 input: raw copy
      uint2 q = *(const uint2*)((const ushort*)X + (size_t)c * NTOT + n0 + u * 4);
      h0 = (ushort)(q.x & 0xffffu); h1 = (ushort)(q.x >> 16);
      h2 = (ushort)(q.y & 0xffffu); h3 = (ushort)(q.y >> 16);
    }
    *(unsigned*)&t16[c][u * 4]     = (unsigned)h0 | ((unsigned)h1 << 16);
    *(unsigned*)&t16[c][u * 4 + 2] = (unsigned)h2 | ((unsigned)h3 << 16);
  }
  __syncthreads();

  // --- MFMA loop: B-fragments gathered straight from t16 ---
  f32x4 acc[OF][4];
#pragma unroll
  for (int a = 0; a < OF; a++)
#pragma unroll
    for (int b = 0; b < 4; b++) acc[a][b] = (f32x4)0.f;
  const int obase = wave * 16 * OF;
#pragma unroll
  for (int ks = 0; ks < 3; ks++) {
    f16x8 bfrag[4];
#pragma unroll
    for (int nf = 0; nf < 4; nf++) {
#pragma unroll
      for (int j = 0; j < 8; j++) {
        // element (k = ks*32+quad*8+j, n = nf*16+col): conflict-free gather
        const ushort* p = &t16[ks * 32 + quad * 8 + j][nf * 16 + col];
        bfrag[nf][j] = *(const _Float16*)p;
      }
    }
#pragma unroll
    for (int of = 0; of < OF; of++) {
      const int o = obase + of * 16 + col;  // A-row = lane&15
      f16x8 afrag = *(const f16x8*)(W + (size_t)o * 96 + ks * 32 + quad * 8);
#pragma unroll
      for (int nf = 0; nf < 4; nf++)
        acc[of][nf] = __builtin_amdgcn_mfma_f32_16x16x32_f16(afrag, bfrag[nf], acc[of][nf], 0, 0, 0);
    }
  }
  // t16 is read until each wave's MFMA loop ends; cs aliases it -> barrier first.
  __syncthreads();
  // C/D layout: col = lane&15 (n), row = quad*4 + r (o). Stage in LDS, coalesced store.
#pragma unroll
  for (int of = 0; of < OF; of++)
#pragma unroll
    for (int nf = 0; nf < 4; nf++)
#pragma unroll
      for (int r = 0; r < 4; r++) {
        int o = obase + of * 16 + quad * 4 + r;
        cs[o][nf * 16 + col] = f2h(acc[of][nf][r]);
      }
  __syncthreads();
  if (!DYNOUT) {
    // f16 out, 16B chunks, nontemporal (written once, consumer >> L2)
#pragma unroll
    for (int i = 0; i < 2 * OF; i++) {
      int idx = tid + 384 * i;
      int o = idx >> 3, u = idx & 7;
      u32x4 v = *(const u32x4*)&cs[o][u * 8];
      __builtin_nontemporal_store(v, (u32x4*)((ushort*)C + (size_t)o * NTOT + n0 + u * 8));
    }
  } else {
#pragma unroll
    for (int i = 0; i < 4; i++) {
      int idx = tid + 384 * i;
      int o = idx >> 4, u = idx & 15;
      uint2 v = *(const uint2*)&cs[o][u * 4];
      __half2 a = u2h(v.x), b = u2h(v.y);
      float f0 = __half2float(a.x), f1 = __half2float(a.y);
      float f2 = __half2float(b.x), f3 = __half2float(b.y);
      if (!f) {
        u32x4 q = { __float_as_uint(f0), __float_as_uint(f1),
                    __float_as_uint(f2), __float_as_uint(f3) };
        __builtin_nontemporal_store(q, (u32x4*)((float*)C + (size_t)o * NTOT + n0 + u * 4));
      } else {
        uint2 q = make_uint2(((unsigned)f2bf(f1) << 16) | f2bf(f0),
                             ((unsigned)f2bf(f3) << 16) | f2bf(f2));
        *(uint2*)((ushort*)C + (size_t)o * NTOT + n0 + u * 4) = q;
      }
    }
  }
}

// depthwise 3x3x3, pad 1, f16 in/out, packed-f16 math.  (R5-proven)
__global__ __launch_bounds__(256)
void dwconv3(const ushort* __restrict__ in, const void* __restrict__ wt,
             ushort* __restrict__ out, const int* __restrict__ flag) {
  const unsigned B = blockIdx.x;           // 0..9215
  const int xcd = B & 7;
  const int s = B >> 3;                    // 0..1151
  const int c = xcd + 8 * (s >> 5);        // 0..287, whole channel per XCD
  const int sp = s & 31;                   // 32 spatial blocks per channel
  const int tid = threadIdx.x;
  const int dq = tid & 7;
  const int w = (sp >> 2) * 8 + ((tid >> 3) & 7);
  const int h0 = (sp & 3) * 16 + (tid >> 6) * 4;   // wave-uniform, 4 rows/thread
  const int d0 = dq * 8;
  __shared__ __half2 wsm2[27];
  if (tid < 27) {
    int f = *flag;
    float wv = f ? bf2f(((const ushort*)wt)[c * 27 + tid])
                 : ((const float*)wt)[c * 27 + tid];
    wsm2[tid] = __floats2half2_rn(wv, wv);
  }
  __syncthreads();
  __half2 wreg[27];
#pragma unroll
  for (int i = 0; i < 27; i++) wreg[i] = wsm2[i];
  const unsigned maskL = (dq == 0) ? 0xFFFF0000u : 0xFFFFFFFFu;  // zero x[-1]
  const unsigned maskR = (dq == 7) ? 0x0000FFFFu : 0xFFFFFFFFu;  // zero x[64]
  __half2 acc[4][4];
#pragma unroll
  for (int r = 0; r < 4; r++)
#pragma unroll
    for (int j = 0; j < 4; j++) acc[r][j] = u2h(0u);
  const size_t cbase = (size_t)c * NTOT;
#pragma unroll
  for (int dw = -1; dw <= 1; dw++) {
    const int ww = w + dw;
    const bool wok = (ww >= 0 && ww <= 63);          // uniform within 8-lane group
    const ushort* rowp = in + cbase + (size_t)ww * 64 + d0;
#pragma unroll
    for (int e = -1; e <= 4; e++) {                  // input rows h0-1 .. h0+4
      const int hh = h0 + e;
      if (hh < 0 || hh > 63) continue;               // wave-uniform
      uint4 u = make_uint4(0u, 0u, 0u, 0u);
      if (wok)
        u = *(const uint4*)(rowp + (size_t)hh * 4096);
      unsigned P = (unsigned)__shfl_up((int)u.w, 1, 8);     // prev lane {x6,x7}
      unsigned N = (unsigned)__shfl_down((int)u.x, 1, 8);   // next lane {x0,x1}
      unsigned S0 = __builtin_amdgcn_perm(u.x, P,   0x05040302) & maskL; // {x-1,x0}
      unsigned S1 = __builtin_amdgcn_perm(u.y, u.x, 0x05040302);         // {x1,x2}
      unsigned S2 = __builtin_amdgcn_perm(u.z, u.y, 0x05040302);         // {x3,x4}
      unsigned S3 = __builtin_amdgcn_perm(u.w, u.z, 0x05040302);         // {x5,x6}
      unsigned R3 = __builtin_amdgcn_perm(N,   u.w, 0x05040302) & maskR; // {x7,x8}
#pragma unroll
      for (int r = (e - 1 < 0 ? 0 : e - 1); r <= (e + 1 > 3 ? 3 : e + 1); r++) {
        const int wb = (e - r + 1) * 9 + (dw + 1) * 3;
        const __half2 wL = wreg[wb], wC = wreg[wb + 1], wR = wreg[wb + 2];
        acc[r][0] = __hfma2(wL, u2h(S0), acc[r][0]); acc[r][0] = __hfma2(wC, u2h(u.x), acc[r][0]); acc[r][0] = __hfma2(wR, u2h(S1), acc[r][0]);
        acc[r][1] = __hfma2(wL, u2h(S1), acc[r][1]); acc[r][1] = __hfma2(wC, u2h(u.y), acc[r][1]); acc[r][1] = __hfma2(wR, u2h(S2), acc[r][1]);
        acc[r][2] = __hfma2(wL, u2h(S2), acc[r][2]); acc[r][2] = __hfma2(wC, u2h(u.z), acc[r][2]); acc[r][2] = __hfma2(wR, u2h(S3), acc[r][2]);
        acc[r][3] = __hfma2(wL, u2h(S3), acc[r][3]); acc[r][3] = __hfma2(wC, u2h(u.w), acc[r][3]); acc[r][3] = __hfma2(wR, u2h(R3), acc[r][3]);
      }
    }
  }
#pragma unroll
  for (int r = 0; r < 4; r++) {
    u32x4 pv = { h2u(acc[r][0]), h2u(acc[r][1]), h2u(acc[r][2]), h2u(acc[r][3]) };
    __builtin_nontemporal_store(pv,
        (u32x4*)(out + cbase + ((size_t)(h0 + r) * 64 + w) * 64 + d0));
  }
}

// per-head Gram: G[hd][0]=q.kT, [1]=q.qT, [2]=k.kT  (each 16x16 fp32, atomic accum)
// 768 blocks (2048 n-range each): 3 blocks/CU for latency hiding.
__global__ __launch_bounds__(256)
void gram16(const ushort* __restrict__ qk, float* __restrict__ G) {
  const int hd = blockIdx.y;
  const int tid = threadIdx.x, wave = tid >> 6, lane = tid & 63;
  const int col = lane & 15, quad = lane >> 4;
  const ushort* qp = qk + (size_t)(hd * 16 + col) * NTOT;
  const ushort* kp = qp + (size_t)96 * NTOT;
  f32x4 aqk = (f32x4)0.f, aqq = (f32x4)0.f, akk = (f32x4)0.f;
  const int nbase = blockIdx.x * 2048 + wave * 32 + quad * 8;
#pragma unroll 4
  for (int it = 0; it < 16; it++) {
    f16x8 qf = *(const f16x8*)(qp + nbase + it * 128);
    f16x8 kf = *(const f16x8*)(kp + nbase + it * 128);
    aqk = __builtin_amdgcn_mfma_f32_16x16x32_f16(qf, kf, aqk, 0, 0, 0);
    aqq = __builtin_amdgcn_mfma_f32_16x16x32_f16(qf, qf, aqq, 0, 0, 0);
    akk = __builtin_amdgcn_mfma_f32_16x16x32_f16(kf, kf, akk, 0, 0, 0);
  }
  __shared__ float red[4][64][12];
#pragma unroll
  for (int r = 0; r < 4; r++) {
    red[wave][lane][r]     = aqk[r];
    red[wave][lane][4 + r] = aqq[r];
    red[wave][lane][8 + r] = akk[r];
  }
  __syncthreads();
  if (wave == 0) {
#pragma unroll
    for (int j = 0; j < 12; j++) {
      float v = red[0][lane][j] + red[1][lane][j] + red[2][lane][j] + red[3][lane][j];
      int sub = j >> 2, r = j & 3;
      atomicAdd(&G[hd * 768 + sub * 256 + (quad * 4 + r) * 16 + col], v);
    }
  }
}

// softmax over Gram + fold W_proj: M[o][hd*16+d] = sum_c wp[o][hd*16+c] * A[hd][c][d]
// 36 blocks: each redundantly computes the tiny softmax and writes one slice.
__global__ __launch_bounds__(256)
void attn_mix(const float* __restrict__ G, const void* __restrict__ wp,
              const void* __restrict__ temp, ushort* __restrict__ M,
              const int* __restrict__ flag) {
  __shared__ float As[6][16][16];
  const int tid = threadIdx.x;
  const int f = *flag;
  if (tid < 96) {
    int hd = tid >> 4, c = tid & 15;
    const float* Gh = G + hd * 768;
    float qn = fmaxf(sqrtf(fmaxf(Gh[256 + c * 17], 0.f)), 1e-12f);
    float t = f ? bf2f(((const ushort*)temp)[hd]) : ((const float*)temp)[hd];
    float lg[16];
    float mx = -1e30f;
#pragma unroll
    for (int d = 0; d < 16; d++) {
      float kn = fmaxf(sqrtf(fmaxf(Gh[512 + d * 17], 0.f)), 1e-12f);
      lg[d] = Gh[c * 16 + d] / (qn * kn) * t;
      mx = fmaxf(mx, lg[d]);
    }
    float s = 0.f;
#pragma unroll
    for (int d = 0; d < 16; d++) { lg[d] = __expf(lg[d] - mx); s += lg[d]; }
    float inv = 1.f / s;
#pragma unroll
    for (int d = 0; d < 16; d++) As[hd][c][d] = lg[d] * inv;
  }
  __syncthreads();
  int idx = blockIdx.x * 256 + tid;    // 36*256 = 9216 = 96*96
  int o = idx / 96, p = idx - o * 96;
  int hd = p >> 4, d = p & 15;
  float s = 0.f;
#pragma unroll
  for (int cc = 0; cc < 16; cc++) {
    float wv = f ? bf2f(((const ushort*)wp)[o * 96 + hd * 16 + cc])
                 : ((const float*)wp)[o * 96 + hd * 16 + cc];
    s += wv * As[hd][cc][d];
  }
  M[idx] = f2h(s);
}

extern "C" void kernel_launch(void* const* d_in, const int* in_sizes, int n_in,
                              void* d_out, int out_size, void* d_ws, size_t ws_size,
                              hipStream_t stream) {
  const void* x      = d_in[0];  // (96, 64,64,64)
  const void* w_qkv  = d_in[1];  // (288, 96)
  const void* w_dw   = d_in[2];  // (288, 27)
  const void* w_proj = d_in[3];  // (96, 96)
  const void* temp   = d_in[4];  // (6)

  const size_t szQKV = (size_t)288 * NTOT * 2;  // 151 MB
  ushort* B1 = (ushort*)d_ws;                   // qkv after 1x1 (f16)
  ushort* B2 = (ushort*)((char*)d_ws + szQKV);  // qkv after dwconv (f16)
  char* tail = (char*)d_ws + 2 * szQKV;
  float*  G    = (float*)tail;                    // 6*768 fp32      (18432 B)
  ushort* M    = (ushort*)(tail + 18432);         // 96*96 f16
  ushort* Wh   = (ushort*)(tail + 36864);         // 288*96 f16      (55296 B)
  int*    flag = (int*)(tail + 92160);
  if (ws_size < 2 * szQKV + 92160 + 256) return;  // fail loudly (zeros out)

  detect_dtype<<<1, 64, 0, stream>>>((const ushort*)w_qkv, flag);
  cvt_f16<<<32, 256, 0, stream>>>(w_qkv, Wh, 288 * 96, flag);
  hipMemsetAsync(G, 0, 4608 * 4, stream);
  gemm96x<3, 0, false><<<4096, 384, 0, stream>>>(Wh, x, B1, flag);
  dwconv3<<<9216, 256, 0, stream>>>(B1, w_dw, B2, flag);
  gram16<<<dim3(128, 6), 256, 0, stream>>>(B2, G);
  attn_mix<<<36, 256, 0, stream>>>(G, w_proj, temp, M, flag);
  gemm96x<1, 1, true><<<4096, 384, 0, stream>>>(M, B2 + (size_t)192 * NTOT, d_out, flag);
}

// Round 10
// 364.048 us; speedup vs baseline: 1.1036x; 1.0555x over previous
//
#include <hip/hip_runtime.h>
#include <hip/hip_bf16.h>
#include <hip/hip_fp16.h>

#define NTOT 262144  // 64*64*64 spatial
typedef __hip_bfloat16 bf16;
typedef __attribute__((ext_vector_type(4))) float f32x4;
typedef _Float16 f16x8 __attribute__((ext_vector_type(8)));
typedef unsigned int u32x4 __attribute__((ext_vector_type(4)));

__device__ inline ushort f2bf(float f){ bf16 b = __float2bfloat16(f); return *(ushort*)&b; }
__device__ inline float bf2f(ushort u){ union{unsigned i;float f;}v; v.i = (unsigned)u<<16; return v.f; }
__device__ inline unsigned h2u(__half2 h){ union{__half2 h; unsigned u;}v; v.h=h; return v.u; }
__device__ inline __half2 u2h(unsigned u){ union{unsigned u; __half2 h;}v; v.u=u; return v.h; }
__device__ inline ushort f2h(float f){ __half h = __float2half_rn(f); return *(ushort*)&h; }

// ---- dtype detector: flag=1 if inputs are bf16, 0 if fp32 ----
__global__ void detect_dtype(const ushort* __restrict__ w, int* __restrict__ flag) {
  int tid = threadIdx.x;  // 64 threads
  int sane = 0;
  for (int i = tid; i < 512; i += 64) {
    ushort u = w[2 * i];
    int e = (u >> 7) & 0xff;
    sane += (e == 0 || (e >= 100 && e <= 140)) ? 1 : 0;
  }
#pragma unroll
  for (int off = 32; off > 0; off >>= 1) sane += __shfl_down(sane, off, 64);
  if (tid == 0) *flag = (sane >= 256) ? 1 : 0;
}

// convert small array (fp32 or bf16 per flag) to f16 bits
__global__ void cvt_f16(const void* __restrict__ in, ushort* __restrict__ outw,
                        int n, const int* __restrict__ flag) {
  int f = *flag;
  for (int i = blockIdx.x * 256 + threadIdx.x; i < n; i += gridDim.x * 256) {
    float v = f ? bf2f(((const ushort*)in)[i]) : ((const float*)in)[i];
    outw[i] = f2h(v);
  }
}

// ===== fused transpose + GEMM, v2b =====
// C[o][n] = sum_c W[o][c] * X[c][n], K=96, O = 96*OF.  W k-major f16 (global);
// X channel-major (MODE 0: fp32/bf16 per flag; MODE 1: f16).
// Phase A stages the 96c x 64n tile into LDS t16[96][66] (f16, stride 33 dwords
// == 1 mod 32).  NO repack pass: the MFMA B-fragments are gathered directly as
// ds_read_u16 from t16 — banks = 8*quad + col/2 (+const) = all 32, col-parity
// pairs share a dword (broadcast) -> conflict-free; all 96 reads are
// compile-time offsets off one lane base.  cs epilogue aliases t16
// (barrier-separated).  B1 output (!DYNOUT) uses CACHED stores: consumer
// dwconv3 reads it 1.18x immediately and 151MB fits L3 — NT here cost dwconv3
// +26us (R7 measured).  Final fp32 output (DYNOUT,!f) uses NT (never re-read).
// 384 threads = 6 waves.
template<int OF, int MODE, bool DYNOUT>
__global__ __launch_bounds__(384)
void gemm96x(const ushort* __restrict__ W, const void* __restrict__ X,
             void* __restrict__ C, const int* __restrict__ flag) {
  constexpr int CSB = 96 * OF * 72 * 2;     // cs bytes
  constexpr int TB  = 96 * 66 * 2;          // t16 bytes (12672)
  constexpr int UNI = (CSB > TB ? CSB : TB);
  __shared__ __align__(16) char smem[UNI];
  ushort (*t16)[66] = (ushort(*)[66])smem;
  ushort (*cs)[72]  = (ushort(*)[72])smem;   // aliases t16 (post-MFMA only)
  const int tid = threadIdx.x;
  const long n0 = (long)blockIdx.x * 64;
  const int wave = tid >> 6, lane = tid & 63;
  const int col = lane & 15, quad = lane >> 4;
  const int f = (MODE == 0 || DYNOUT) ? *flag : 0;

  // --- phase A: stage [96][64] tile as f16 into t16 ---
#pragma unroll
  for (int i = 0; i < 4; i++) {
    int idx = tid + 384 * i;      // 0..1535
    int u = idx & 15, c = idx >> 4;
    ushort h0, h1, h2, h3;
    if (MODE == 0 && !f) {
      float4 q = *(const float4*)((const float*)X + (size_t)c * NTOT + n0 + u * 4);
      h0 = f2h(q.x); h1 = f2h(q.y); h2 = f2h(q.z); h3 = f2h(q.w);
    } else if (MODE == 0) {       // bf16 input
      uint2 q = *(const uint2*)((const ushort*)X + (size_t)c * NTOT + n0 + u * 4);
      h0 = f2h(bf2f((ushort)(q.x & 0xffffu))); h1 = f2h(bf2f((ushort)(q.x >> 16)));
      h2 = f2h(bf2f((ushort)(q.y & 0xffffu))); h3 = f2h(bf2f((ushort)(q.y >> 16)));
    } else {                      // f16 input: raw copy
      uint2 q = *(const uint2*)((const ushort*)X + (size_t)c * NTOT + n0 + u * 4);
      h0 = (ushort)(q.x & 0xffffu); h1 = (ushort)(q.x >> 16);
      h2 = (ushort)(q.y & 0xffffu); h3 = (ushort)(q.y >> 16);
    }
    *(unsigned*)&t16[c][u * 4]     = (unsigned)h0 | ((unsigned)h1 << 16);
    *(unsigned*)&t16[c][u * 4 + 2] = (unsigned)h2 | ((unsigned)h3 << 16);
  }
  __syncthreads();

  // --- MFMA loop: B-fragments gathered straight from t16 ---
  f32x4 acc[OF][4];
#pragma unroll
  for (int a = 0; a < OF; a++)
#pragma unroll
    for (int b = 0; b < 4; b++) acc[a][b] = (f32x4)0.f;
  const int obase = wave * 16 * OF;
#pragma unroll
  for (int ks = 0; ks < 3; ks++) {
    f16x8 bfrag[4];
#pragma unroll
    for (int nf = 0; nf < 4; nf++) {
#pragma unroll
      for (int j = 0; j < 8; j++) {
        // element (k = ks*32+quad*8+j, n = nf*16+col): conflict-free gather
        const ushort* p = &t16[ks * 32 + quad * 8 + j][nf * 16 + col];
        bfrag[nf][j] = *(const _Float16*)p;
      }
    }
#pragma unroll
    for (int of = 0; of < OF; of++) {
      const int o = obase + of * 16 + col;  // A-row = lane&15
      f16x8 afrag = *(const f16x8*)(W + (size_t)o * 96 + ks * 32 + quad * 8);
#pragma unroll
      for (int nf = 0; nf < 4; nf++)
        acc[of][nf] = __builtin_amdgcn_mfma_f32_16x16x32_f16(afrag, bfrag[nf], acc[of][nf], 0, 0, 0);
    }
  }
  // t16 is read until each wave's MFMA loop ends; cs aliases it -> barrier first.
  __syncthreads();
  // C/D layout: col = lane&15 (n), row = quad*4 + r (o). Stage in LDS, coalesced store.
#pragma unroll
  for (int of = 0; of < OF; of++)
#pragma unroll
    for (int nf = 0; nf < 4; nf++)
#pragma unroll
      for (int r = 0; r < 4; r++) {
        int o = obase + of * 16 + quad * 4 + r;
        cs[o][nf * 16 + col] = f2h(acc[of][nf][r]);
      }
  __syncthreads();
  if (!DYNOUT) {
    // f16 out, 16B chunks, CACHED (consumer dwconv3 reads immediately; fits L3)
#pragma unroll
    for (int i = 0; i < 2 * OF; i++) {
      int idx = tid + 384 * i;
      int o = idx >> 3, u = idx & 7;
      uint4 v = *(const uint4*)&cs[o][u * 8];
      *(uint4*)((ushort*)C + (size_t)o * NTOT + n0 + u * 8) = v;
    }
  } else {
#pragma unroll
    for (int i = 0; i < 4; i++) {
      int idx = tid + 384 * i;
      int o = idx >> 4, u = idx & 15;
      uint2 v = *(const uint2*)&cs[o][u * 4];
      __half2 a = u2h(v.x), b = u2h(v.y);
      float f0 = __half2float(a.x), f1 = __half2float(a.y);
      float f2 = __half2float(b.x), f3 = __half2float(b.y);
      if (!f) {
        u32x4 q = { __float_as_uint(f0), __float_as_uint(f1),
                    __float_as_uint(f2), __float_as_uint(f3) };
        __builtin_nontemporal_store(q, (u32x4*)((float*)C + (size_t)o * NTOT + n0 + u * 4));
      } else {
        uint2 q = make_uint2(((unsigned)f2bf(f1) << 16) | f2bf(f0),
                             ((unsigned)f2bf(f3) << 16) | f2bf(f2));
        *(uint2*)((ushort*)C + (size_t)o * NTOT + n0 + u * 4) = q;
      }
    }
  }
}

// depthwise 3x3x3, pad 1, f16 in/out, packed-f16 math.  (R5-proven)
__global__ __launch_bounds__(256)
void dwconv3(const ushort* __restrict__ in, const void* __restrict__ wt,
             ushort* __restrict__ out, const int* __restrict__ flag) {
  const unsigned B = blockIdx.x;           // 0..9215
  const int xcd = B & 7;
  const int s = B >> 3;                    // 0..1151
  const int c = xcd + 8 * (s >> 5);        // 0..287, whole channel per XCD
  const int sp = s & 31;                   // 32 spatial blocks per channel
  const int tid = threadIdx.x;
  const int dq = tid & 7;
  const int w = (sp >> 2) * 8 + ((tid >> 3) & 7);
  const int h0 = (sp & 3) * 16 + (tid >> 6) * 4;   // wave-uniform, 4 rows/thread
  const int d0 = dq * 8;
  __shared__ __half2 wsm2[27];
  if (tid < 27) {
    int f = *flag;
    float wv = f ? bf2f(((const ushort*)wt)[c * 27 + tid])
                 : ((const float*)wt)[c * 27 + tid];
    wsm2[tid] = __floats2half2_rn(wv, wv);
  }
  __syncthreads();
  __half2 wreg[27];
#pragma unroll
  for (int i = 0; i < 27; i++) wreg[i] = wsm2[i];
  const unsigned maskL = (dq == 0) ? 0xFFFF0000u : 0xFFFFFFFFu;  // zero x[-1]
  const unsigned maskR = (dq == 7) ? 0x0000FFFFu : 0xFFFFFFFFu;  // zero x[64]
  __half2 acc[4][4];
#pragma unroll
  for (int r = 0; r < 4; r++)
#pragma unroll
    for (int j = 0; j < 4; j++) acc[r][j] = u2h(0u);
  const size_t cbase = (size_t)c * NTOT;
#pragma unroll
  for (int dw = -1; dw <= 1; dw++) {
    const int ww = w + dw;
    const bool wok = (ww >= 0 && ww <= 63);          // uniform within 8-lane group
    const ushort* rowp = in + cbase + (size_t)ww * 64 + d0;
#pragma unroll
    for (int e = -1; e <= 4; e++) {                  // input rows h0-1 .. h0+4
      const int hh = h0 + e;
      if (hh < 0 || hh > 63) continue;               // wave-uniform
      uint4 u = make_uint4(0u, 0u, 0u, 0u);
      if (wok)
        u = *(const uint4*)(rowp + (size_t)hh * 4096);
      unsigned P = (unsigned)__shfl_up((int)u.w, 1, 8);     // prev lane {x6,x7}
      unsigned N = (unsigned)__shfl_down((int)u.x, 1, 8);   // next lane {x0,x1}
      unsigned S0 = __builtin_amdgcn_perm(u.x, P,   0x05040302) & maskL; // {x-1,x0}
      unsigned S1 = __builtin_amdgcn_perm(u.y, u.x, 0x05040302);         // {x1,x2}
      unsigned S2 = __builtin_amdgcn_perm(u.z, u.y, 0x05040302);         // {x3,x4}
      unsigned S3 = __builtin_amdgcn_perm(u.w, u.z, 0x05040302);         // {x5,x6}
      unsigned R3 = __builtin_amdgcn_perm(N,   u.w, 0x05040302) & maskR; // {x7,x8}
#pragma unroll
      for (int r = (e - 1 < 0 ? 0 : e - 1); r <= (e + 1 > 3 ? 3 : e + 1); r++) {
        const int wb = (e - r + 1) * 9 + (dw + 1) * 3;
        const __half2 wL = wreg[wb], wC = wreg[wb + 1], wR = wreg[wb + 2];
        acc[r][0] = __hfma2(wL, u2h(S0), acc[r][0]); acc[r][0] = __hfma2(wC, u2h(u.x), acc[r][0]); acc[r][0] = __hfma2(wR, u2h(S1), acc[r][0]);
        acc[r][1] = __hfma2(wL, u2h(S1), acc[r][1]); acc[r][1] = __hfma2(wC, u2h(u.y), acc[r][1]); acc[r][1] = __hfma2(wR, u2h(S2), acc[r][1]);
        acc[r][2] = __hfma2(wL, u2h(S2), acc[r][2]); acc[r][2] = __hfma2(wC, u2h(u.z), acc[r][2]); acc[r][2] = __hfma2(wR, u2h(S3), acc[r][2]);
        acc[r][3] = __hfma2(wL, u2h(S3), acc[r][3]); acc[r][3] = __hfma2(wC, u2h(u.w), acc[r][3]); acc[r][3] = __hfma2(wR, u2h(R3), acc[r][3]);
      }
    }
  }
#pragma unroll
  for (int r = 0; r < 4; r++) {
    u32x4 pv = { h2u(acc[r][0]), h2u(acc[r][1]), h2u(acc[r][2]), h2u(acc[r][3]) };
    __builtin_nontemporal_store(pv,
        (u32x4*)(out + cbase + ((size_t)(h0 + r) * 64 + w) * 64 + d0));
  }
}

// per-head Gram: G[hd][0]=q.kT, [1]=q.qT, [2]=k.kT  (each 16x16 fp32, atomic accum)
// 768 blocks (2048 n-range each): 3 blocks/CU for latency hiding.
__global__ __launch_bounds__(256)
void gram16(const ushort* __restrict__ qk, float* __restrict__ G) {
  const int hd = blockIdx.y;
  const int tid = threadIdx.x, wave = tid >> 6, lane = tid & 63;
  const int col = lane & 15, quad = lane >> 4;
  const ushort* qp = qk + (size_t)(hd * 16 + col) * NTOT;
  const ushort* kp = qp + (size_t)96 * NTOT;
  f32x4 aqk = (f32x4)0.f, aqq = (f32x4)0.f, akk = (f32x4)0.f;
  const int nbase = blockIdx.x * 2048 + wave * 32 + quad * 8;
#pragma unroll 4
  for (int it = 0; it < 16; it++) {
    f16x8 qf = *(const f16x8*)(qp + nbase + it * 128);
    f16x8 kf = *(const f16x8*)(kp + nbase + it * 128);
    aqk = __builtin_amdgcn_mfma_f32_16x16x32_f16(qf, kf, aqk, 0, 0, 0);
    aqq = __builtin_amdgcn_mfma_f32_16x16x32_f16(qf, qf, aqq, 0, 0, 0);
    akk = __builtin_amdgcn_mfma_f32_16x16x32_f16(kf, kf, akk, 0, 0, 0);
  }
  __shared__ float red[4][64][12];
#pragma unroll
  for (int r = 0; r < 4; r++) {
    red[wave][lane][r]     = aqk[r];
    red[wave][lane][4 + r] = aqq[r];
    red[wave][lane][8 + r] = akk[r];
  }
  __syncthreads();
  if (wave == 0) {
#pragma unroll
    for (int j = 0; j < 12; j++) {
      float v = red[0][lane][j] + red[1][lane][j] + red[2][lane][j] + red[3][lane][j];
      int sub = j >> 2, r = j & 3;
      atomicAdd(&G[hd * 768 + sub * 256 + (quad * 4 + r) * 16 + col], v);
    }
  }
}

// softmax over Gram + fold W_proj: M[o][hd*16+d] = sum_c wp[o][hd*16+c] * A[hd][c][d]
// 36 blocks: each redundantly computes the tiny softmax and writes one slice.
__global__ __launch_bounds__(256)
void attn_mix(const float* __restrict__ G, const void* __restrict__ wp,
              const void* __restrict__ temp, ushort* __restrict__ M,
              const int* __restrict__ flag) {
  __shared__ float As[6][16][16];
  const int tid = threadIdx.x;
  const int f = *flag;
  if (tid < 96) {
    int hd = tid >> 4, c = tid & 15;
    const float* Gh = G + hd * 768;
    float qn = fmaxf(sqrtf(fmaxf(Gh[256 + c * 17], 0.f)), 1e-12f);
    float t = f ? bf2f(((const ushort*)temp)[hd]) : ((const float*)temp)[hd];
    float lg[16];
    float mx = -1e30f;
#pragma unroll
    for (int d = 0; d < 16; d++) {
      float kn = fmaxf(sqrtf(fmaxf(Gh[512 + d * 17], 0.f)), 1e-12f);
      lg[d] = Gh[c * 16 + d] / (qn * kn) * t;
      mx = fmaxf(mx, lg[d]);
    }
    float s = 0.f;
#pragma unroll
    for (int d = 0; d < 16; d++) { lg[d] = __expf(lg[d] - mx); s += lg[d]; }
    float inv = 1.f / s;
#pragma unroll
    for (int d = 0; d < 16; d++) As[hd][c][d] = lg[d] * inv;
  }
  __syncthreads();
  int idx = blockIdx.x * 256 + tid;    // 36*256 = 9216 = 96*96
  int o = idx / 96, p = idx - o * 96;
  int hd = p >> 4, d = p & 15;
  float s = 0.f;
#pragma unroll
  for (int cc = 0; cc < 16; cc++) {
    float wv = f ? bf2f(((const ushort*)wp)[o * 96 + hd * 16 + cc])
                 : ((const float*)wp)[o * 96 + hd * 16 + cc];
    s += wv * As[hd][cc][d];
  }
  M[idx] = f2h(s);
}

extern "C" void kernel_launch(void* const* d_in, const int* in_sizes, int n_in,
                              void* d_out, int out_size, void* d_ws, size_t ws_size,
                              hipStream_t stream) {
  const void* x      = d_in[0];  // (96, 64,64,64)
  const void* w_qkv  = d_in[1];  // (288, 96)
  const void* w_dw   = d_in[2];  // (288, 27)
  const void* w_proj = d_in[3];  // (96, 96)
  const void* temp   = d_in[4];  // (6)

  const size_t szQKV = (size_t)288 * NTOT * 2;  // 151 MB
  ushort* B1 = (ushort*)d_ws;                   // qkv after 1x1 (f16)
  ushort* B2 = (ushort*)((char*)d_ws + szQKV);  // qkv after dwconv (f16)
  char* tail = (char*)d_ws + 2 * szQKV;
  float*  G    = (float*)tail;                    // 6*768 fp32      (18432 B)
  ushort* M    = (ushort*)(tail + 18432);         // 96*96 f16
  ushort* Wh   = (ushort*)(tail + 36864);         // 288*96 f16      (55296 B)
  int*    flag = (int*)(tail + 92160);
  if (ws_size < 2 * szQKV + 92160 + 256) return;  // fail loudly (zeros out)

  detect_dtype<<<1, 64, 0, stream>>>((const ushort*)w_qkv, flag);
  cvt_f16<<<32, 256, 0, stream>>>(w_qkv, Wh, 288 * 96, flag);
  hipMemsetAsync(G, 0, 4608 * 4, stream);
  gemm96x<3, 0, false><<<4096, 384, 0, stream>>>(Wh, x, B1, flag);
  dwconv3<<<9216, 256, 0, stream>>>(B1, w_dw, B2, flag);
  gram16<<<dim3(128, 6), 256, 0, stream>>>(B2, G);
  attn_mix<<<36, 256, 0, stream>>>(G, w_proj, temp, M, flag);
  gemm96x<1, 1, true><<<4096, 384, 0, stream>>>(M, B2 + (size_t)192 * NTOT, d_out, flag);
}